// Round 1
// baseline (313.130 us; speedup 1.0000x reference)
//
#include <hip/hip_runtime.h>

// Problem constants (from reference setup_inputs)
#define BB 2
#define CC 2
#define DD 160
#define HH 192
#define WW 224
#define DHW (DD * HH * WW)

__global__ __launch_bounds__(256) void affine_sample_kernel(
    const float* __restrict__ src,   // [B,C,D,H,W]
    const float* __restrict__ mat,   // [B,3,4]
    float* __restrict__ out)         // [B,C,D,H,W]
{
    int idx = blockIdx.x * blockDim.x + threadIdx.x;
    if (idx >= DHW) return;
    int b = blockIdx.y;

    int w = idx % WW;
    int t = idx / WW;
    int h = t % HH;
    int d = t / HH;

    // theta = mat with translation column normalized per-row by (D,H,W)
    const float* m = mat + b * 12;
    float a00 = m[0], a01 = m[1], a02 = m[2],  a03 = m[3]  * (1.0f / (float)DD);
    float a10 = m[4], a11 = m[5], a12 = m[6],  a13 = m[7]  * (1.0f / (float)HH);
    float a20 = m[8], a21 = m[9], a22 = m[10], a23 = m[11] * (1.0f / (float)WW);

    float xn = -1.0f + (float)w * (2.0f / (float)(WW - 1));
    float yn = -1.0f + (float)h * (2.0f / (float)(HH - 1));
    float zn = -1.0f + (float)d * (2.0f / (float)(DD - 1));

    // grid: row0 -> gx (~W axis), row1 -> gy (~H), row2 -> gz (~D)
    float gx = a00 * xn + a01 * yn + a02 * zn + a03;
    float gy = a10 * xn + a11 * yn + a12 * zn + a13;
    float gz = a20 * xn + a21 * yn + a22 * zn + a23;

    // unnormalize, align_corners=True
    float ix = (gx + 1.0f) * ((float)(WW - 1) * 0.5f);
    float iy = (gy + 1.0f) * ((float)(HH - 1) * 0.5f);
    float iz = (gz + 1.0f) * ((float)(DD - 1) * 0.5f);

    float fx0 = floorf(ix), fy0 = floorf(iy), fz0 = floorf(iz);
    float fx = ix - fx0, fy = iy - fy0, fz = iz - fz0;
    int x0 = (int)fx0, y0 = (int)fy0, z0 = (int)fz0;

    const float* s0 = src + (size_t)b * CC * DHW;  // channel 0 plane
    const float* s1 = s0 + DHW;                    // channel 1 plane

    float acc0 = 0.0f, acc1 = 0.0f;

    #pragma unroll
    for (int dz = 0; dz < 2; ++dz) {
        int zc = z0 + dz;
        bool vz = (zc >= 0) && (zc < DD);
        float wz = dz ? fz : (1.0f - fz);
        #pragma unroll
        for (int dy = 0; dy < 2; ++dy) {
            int yc = y0 + dy;
            bool vy = (yc >= 0) && (yc < HH);
            float wy = dy ? fy : (1.0f - fy);
            float wzy = wz * wy;
            #pragma unroll
            for (int dx = 0; dx < 2; ++dx) {
                int xc = x0 + dx;
                bool vx = (xc >= 0) && (xc < WW);
                float wgt = wzy * (dx ? fx : (1.0f - fx));
                if (vz && vy && vx) {
                    int lin = (zc * HH + yc) * WW + xc;
                    acc0 += wgt * s0[lin];
                    acc1 += wgt * s1[lin];
                }
            }
        }
    }

    float* o = out + (size_t)b * CC * DHW + idx;
    o[0]   = acc0;
    o[DHW] = acc1;
}

extern "C" void kernel_launch(void* const* d_in, const int* in_sizes, int n_in,
                              void* d_out, int out_size, void* d_ws, size_t ws_size,
                              hipStream_t stream) {
    const float* src = (const float*)d_in[0];
    const float* mat = (const float*)d_in[1];
    float* out = (float*)d_out;

    dim3 block(256);
    dim3 grid((DHW + 255) / 256, BB);
    affine_sample_kernel<<<grid, block, 0, stream>>>(src, mat, out);
}

// Round 2
// 277.490 us; speedup vs baseline: 1.1284x; 1.1284x over previous
//
#include <hip/hip_runtime.h>

// Problem constants (from reference setup_inputs)
#define BB 2
#define CC 2
#define DD 160
#define HH 192
#define WW 224
#define DHW (DD * HH * WW)

__global__ __launch_bounds__(256) void affine_sample_kernel(
    const float* __restrict__ src,   // [B,C,D,H,W]
    const float* __restrict__ mat,   // [B,3,4]
    float* __restrict__ out)         // [B,C,D,H,W]
{
    int idx = blockIdx.x * blockDim.x + threadIdx.x;
    if (idx >= DHW) return;
    int b = blockIdx.y;

    int w = idx % WW;
    int t = idx / WW;
    int h = t % HH;
    int d = t / HH;

    // theta = mat with translation column normalized per-row by (D,H,W)
    const float* m = mat + b * 12;
    float a00 = m[0], a01 = m[1], a02 = m[2],  a03 = m[3]  * (1.0f / (float)DD);
    float a10 = m[4], a11 = m[5], a12 = m[6],  a13 = m[7]  * (1.0f / (float)HH);
    float a20 = m[8], a21 = m[9], a22 = m[10], a23 = m[11] * (1.0f / (float)WW);

    float xn = -1.0f + (float)w * (2.0f / (float)(WW - 1));
    float yn = -1.0f + (float)h * (2.0f / (float)(HH - 1));
    float zn = -1.0f + (float)d * (2.0f / (float)(DD - 1));

    float gx = a00 * xn + a01 * yn + a02 * zn + a03;
    float gy = a10 * xn + a11 * yn + a12 * zn + a13;
    float gz = a20 * xn + a21 * yn + a22 * zn + a23;

    // unnormalize, align_corners=True
    float ix = (gx + 1.0f) * ((float)(WW - 1) * 0.5f);
    float iy = (gy + 1.0f) * ((float)(HH - 1) * 0.5f);
    float iz = (gz + 1.0f) * ((float)(DD - 1) * 0.5f);

    float fx0 = floorf(ix), fy0 = floorf(iy), fz0 = floorf(iz);
    float fx = ix - fx0, fy = iy - fy0, fz = iz - fz0;
    int x0 = (int)fx0, y0 = (int)fy0, z0 = (int)fz0;
    int x1 = x0 + 1, y1 = y0 + 1, z1 = z0 + 1;

    // 1-D weights with boundary validity folded in (tap weight = wz*wy*wx
    // is automatically 0 for any out-of-bounds corner)
    float wx0 = (x0 >= 0 && x0 < WW) ? (1.0f - fx) : 0.0f;
    float wx1 = (x1 >= 0 && x1 < WW) ? fx          : 0.0f;
    float wy0 = (y0 >= 0 && y0 < HH) ? (1.0f - fy) : 0.0f;
    float wy1 = (y1 >= 0 && y1 < HH) ? fy          : 0.0f;
    float wz0 = (z0 >= 0 && z0 < DD) ? (1.0f - fz) : 0.0f;
    float wz1 = (z1 >= 0 && z1 < DD) ? fz          : 0.0f;

    // clamped indices — always safe to load
    int xc0 = min(max(x0, 0), WW - 1), xc1 = min(max(x1, 0), WW - 1);
    int yc0 = min(max(y0, 0), HH - 1), yc1 = min(max(y1, 0), HH - 1);
    int zc0 = min(max(z0, 0), DD - 1), zc1 = min(max(z1, 0), DD - 1);

    const float* s0 = src + (size_t)b * CC * DHW;  // channel 0
    const float* s1 = s0 + DHW;                    // channel 1

    int r00 = (zc0 * HH + yc0) * WW;
    int r01 = (zc0 * HH + yc1) * WW;
    int r10 = (zc1 * HH + yc0) * WW;
    int r11 = (zc1 * HH + yc1) * WW;

    // all 16 loads issued unconditionally, back-to-back
    float v000a = s0[r00 + xc0], v001a = s0[r00 + xc1];
    float v010a = s0[r01 + xc0], v011a = s0[r01 + xc1];
    float v100a = s0[r10 + xc0], v101a = s0[r10 + xc1];
    float v110a = s0[r11 + xc0], v111a = s0[r11 + xc1];
    float v000b = s1[r00 + xc0], v001b = s1[r00 + xc1];
    float v010b = s1[r01 + xc0], v011b = s1[r01 + xc1];
    float v100b = s1[r10 + xc0], v101b = s1[r10 + xc1];
    float v110b = s1[r11 + xc0], v111b = s1[r11 + xc1];

    float w00 = wz0 * wy0, w01 = wz0 * wy1;
    float w10 = wz1 * wy0, w11 = wz1 * wy1;

    float w000 = w00 * wx0, w001 = w00 * wx1;
    float w010 = w01 * wx0, w011 = w01 * wx1;
    float w100 = w10 * wx0, w101 = w10 * wx1;
    float w110 = w11 * wx0, w111 = w11 * wx1;

    float acc0 = w000 * v000a + w001 * v001a + w010 * v010a + w011 * v011a
               + w100 * v100a + w101 * v101a + w110 * v110a + w111 * v111a;
    float acc1 = w000 * v000b + w001 * v001b + w010 * v010b + w011 * v011b
               + w100 * v100b + w101 * v101b + w110 * v110b + w111 * v111b;

    float* o = out + (size_t)b * CC * DHW + idx;
    __builtin_nontemporal_store(acc0, o);
    __builtin_nontemporal_store(acc1, o + DHW);
}

extern "C" void kernel_launch(void* const* d_in, const int* in_sizes, int n_in,
                              void* d_out, int out_size, void* d_ws, size_t ws_size,
                              hipStream_t stream) {
    const float* src = (const float*)d_in[0];
    const float* mat = (const float*)d_in[1];
    float* out = (float*)d_out;

    dim3 block(256);
    dim3 grid((DHW + 255) / 256, BB);
    affine_sample_kernel<<<grid, block, 0, stream>>>(src, mat, out);
}

// Round 3
// 250.921 us; speedup vs baseline: 1.2479x; 1.1059x over previous
//
#include <hip/hip_runtime.h>

// Problem constants (from reference setup_inputs)
#define BB 2
#define CC 2
#define DD 160
#define HH 192
#define WW 224
#define DHW (DD * HH * WW)

typedef float f2v __attribute__((ext_vector_type(2)));

// 8-byte load at a 4-byte-aligned address. gfx950 global loads support
// unaligned addresses; packed struct tells the compiler align==1 so it
// makes a legal instruction choice (dwordx2 if allowed, else 2x dword).
__device__ __forceinline__ f2v load2u(const float* p) {
    struct __attribute__((packed)) S { f2v v; };
    return ((const S*)p)->v;
}

__global__ __launch_bounds__(256) void affine_sample_kernel(
    const float* __restrict__ src,   // [B,C,D,H,W]
    const float* __restrict__ mat,   // [B,3,4]
    float* __restrict__ out)         // [B,C,D,H,W]
{
    int idx = blockIdx.x * blockDim.x + threadIdx.x;
    if (idx >= DHW) return;
    int b = blockIdx.y;

    int w = idx % WW;
    int t = idx / WW;
    int h = t % HH;
    int d = t / HH;

    // theta = mat with translation column normalized per-row by (D,H,W)
    const float* m = mat + b * 12;
    float a00 = m[0], a01 = m[1], a02 = m[2],  a03 = m[3]  * (1.0f / (float)DD);
    float a10 = m[4], a11 = m[5], a12 = m[6],  a13 = m[7]  * (1.0f / (float)HH);
    float a20 = m[8], a21 = m[9], a22 = m[10], a23 = m[11] * (1.0f / (float)WW);

    float xn = -1.0f + (float)w * (2.0f / (float)(WW - 1));
    float yn = -1.0f + (float)h * (2.0f / (float)(HH - 1));
    float zn = -1.0f + (float)d * (2.0f / (float)(DD - 1));

    float gx = a00 * xn + a01 * yn + a02 * zn + a03;
    float gy = a10 * xn + a11 * yn + a12 * zn + a13;
    float gz = a20 * xn + a21 * yn + a22 * zn + a23;

    // unnormalize, align_corners=True
    float ix = (gx + 1.0f) * ((float)(WW - 1) * 0.5f);
    float iy = (gy + 1.0f) * ((float)(HH - 1) * 0.5f);
    float iz = (gz + 1.0f) * ((float)(DD - 1) * 0.5f);

    float fx0 = floorf(ix), fy0 = floorf(iy), fz0 = floorf(iz);
    float fx = ix - fx0, fy = iy - fy0, fz = iz - fz0;
    int x0 = (int)fx0, y0 = (int)fy0, z0 = (int)fz0;
    int x1 = x0 + 1, y1 = y0 + 1, z1 = z0 + 1;

    // 1-D weights with boundary validity folded in
    float wx0 = (x0 >= 0 && x0 < WW) ? (1.0f - fx) : 0.0f;
    float wx1 = (x1 >= 0 && x1 < WW) ? fx          : 0.0f;
    float wy0 = (y0 >= 0 && y0 < HH) ? (1.0f - fy) : 0.0f;
    float wy1 = (y1 >= 0 && y1 < HH) ? fy          : 0.0f;
    float wz0 = (z0 >= 0 && z0 < DD) ? (1.0f - fz) : 0.0f;
    float wz1 = (z1 >= 0 && z1 < DD) ? fz          : 0.0f;

    // clamped indices — always safe to load
    int xc0 = min(max(x0, 0), WW - 1), xc1 = min(max(x1, 0), WW - 1);
    int yc0 = min(max(y0, 0), HH - 1), yc1 = min(max(y1, 0), HH - 1);
    int zc0 = min(max(z0, 0), DD - 1), zc1 = min(max(z1, 0), DD - 1);

    // x-pair base: one 8B load covers both x corners; selects fix clamp cases
    int xb   = min(xc0, WW - 2);     // in [0, WW-2] -> loads always in-bounds
    int sel0 = xc0 - xb;             // 0 or 1
    int sel1 = xc1 - xb;             // 0 or 1

    const float* s0 = src + (size_t)b * CC * DHW + xb;  // channel 0 (+x base)
    const float* s1 = s0 + DHW;                         // channel 1

    int r00 = (zc0 * HH + yc0) * WW;
    int r01 = (zc0 * HH + yc1) * WW;
    int r10 = (zc1 * HH + yc0) * WW;
    int r11 = (zc1 * HH + yc1) * WW;

    // 8 gathers (was 16), issued back-to-back
    f2v pa00 = load2u(s0 + r00);
    f2v pa01 = load2u(s0 + r01);
    f2v pa10 = load2u(s0 + r10);
    f2v pa11 = load2u(s0 + r11);
    f2v pb00 = load2u(s1 + r00);
    f2v pb01 = load2u(s1 + r01);
    f2v pb10 = load2u(s1 + r10);
    f2v pb11 = load2u(s1 + r11);

    float w00 = wz0 * wy0, w01 = wz0 * wy1;
    float w10 = wz1 * wy0, w11 = wz1 * wy1;

    // per-row x-interpolation with clamp-aware selects
    #define ROWVAL(p) (wx0 * (sel0 ? (p)[1] : (p)[0]) + wx1 * (sel1 ? (p)[1] : (p)[0]))
    float acc0 = w00 * ROWVAL(pa00) + w01 * ROWVAL(pa01)
               + w10 * ROWVAL(pa10) + w11 * ROWVAL(pa11);
    float acc1 = w00 * ROWVAL(pb00) + w01 * ROWVAL(pb01)
               + w10 * ROWVAL(pb10) + w11 * ROWVAL(pb11);
    #undef ROWVAL

    float* o = out + (size_t)b * CC * DHW + idx;
    __builtin_nontemporal_store(acc0, o);
    __builtin_nontemporal_store(acc1, o + DHW);
}

extern "C" void kernel_launch(void* const* d_in, const int* in_sizes, int n_in,
                              void* d_out, int out_size, void* d_ws, size_t ws_size,
                              hipStream_t stream) {
    const float* src = (const float*)d_in[0];
    const float* mat = (const float*)d_in[1];
    float* out = (float*)d_out;

    dim3 block(256);
    dim3 grid((DHW + 255) / 256, BB);
    affine_sample_kernel<<<grid, block, 0, stream>>>(src, mat, out);
}